// Round 11
// baseline (1004.124 us; speedup 1.0000x reference)
//
#include <hip/hip_runtime.h>
#include <math.h>

typedef unsigned int u32;
typedef unsigned short u16;
typedef __attribute__((ext_vector_type(4))) float f32x4;
typedef __attribute__((ext_vector_type(8))) short s16x8;

#define NTOT 1048576
#define SWZ(n, col) ((col) ^ (((n) & 7) << 4))

__device__ __forceinline__ float bflo(u32 v) { return __uint_as_float(v << 16); }
__device__ __forceinline__ float bfhi(u32 v) { return __uint_as_float(v & 0xffff0000u); }
// RTNE f32->bf16 pair pack (bit-identical to R3 manual sequence; final select is
// one v_perm_b32).  Do NOT use v_cvt_pk_bf16_f32 (non-RNE -> R4 fail).
__device__ __forceinline__ u32 rndbf(float f) {
  u32 u = __float_as_uint(f);
  return u + 0x7fffu + ((u >> 16) & 1u);
}
__device__ __forceinline__ u32 pk2(float a, float b) {
  return __builtin_amdgcn_perm(rndbf(b), rndbf(a), 0x07060302u);
}
__device__ __forceinline__ s16x8 pack8(const float m[8]) {
  union { u32 w[4]; s16x8 v; } cv;
  cv.w[0] = pk2(m[0], m[1]); cv.w[1] = pk2(m[2], m[3]);
  cv.w[2] = pk2(m[4], m[5]); cv.w[3] = pk2(m[6], m[7]);
  return cv.v;
}
__device__ __forceinline__ float sigm(float x) {
  return __builtin_amdgcn_rcpf(1.0f + __expf(-x));
}
__device__ __forceinline__ float tanh_f(float x) {
  float e = __expf(2.0f * x);
  return 1.0f - 2.0f * __builtin_amdgcn_rcpf(e + 1.0f);
}
__device__ __forceinline__ float relu(float x) { return fmaxf(x, 0.0f); }

// ---------- MFMA GEMM micro-kernels ----------
// A: fragment-ordered weights from GLOBAL (L2-resident); sched_barrier(0) fences
// between gates stop the all-gates A-load hoist (R6/R7 scratch spill lesson).
// gemmR: B-operand fragments already in REGISTERS (bf[nt*2+kb]).
__device__ __forceinline__ void gemmR(const ushort* __restrict__ gA,
                                      const s16x8 bf[8],
                                      int ws, int l, f32x4 acc[4]) {
  s16x8 a0 = *(const s16x8*)(gA + ((ws * 128 + l) << 3));
  s16x8 a1 = *(const s16x8*)(gA + ((ws * 128 + 64 + l) << 3));
#pragma unroll
  for (int nt = 0; nt < 4; ++nt) {
    acc[nt] = __builtin_amdgcn_mfma_f32_16x16x32_bf16(a0, bf[nt * 2 + 0], acc[nt], 0, 0, 0);
    acc[nt] = __builtin_amdgcn_mfma_f32_16x16x32_bf16(a1, bf[nt * 2 + 1], acc[nt], 0, 0, 0);
  }
}

// gemmG: B-operand from LDS [node][128B] XOR-swizzled at L+boff (for the two
// true cross-wave transposes: h (P) and u (U)).
__device__ __forceinline__ void gemmG(const ushort* __restrict__ gA,
                                      const unsigned char* L, int boff,
                                      int ws, int l, int lq, int lr,
                                      f32x4 acc[4]) {
  s16x8 a0 = *(const s16x8*)(gA + ((ws * 128 + l) << 3));
  s16x8 a1 = *(const s16x8*)(gA + ((ws * 128 + 64 + l) << 3));
  const int c0 = (lq << 4) ^ ((lr & 7) << 4);
  const unsigned char* Bp = L + boff + lr * 128;
#pragma unroll
  for (int nt = 0; nt < 4; ++nt) {
    s16x8 b0 = *(const s16x8*)(Bp + nt * 2048 + c0);
    s16x8 b1 = *(const s16x8*)(Bp + nt * 2048 + (c0 ^ 64));
    acc[nt] = __builtin_amdgcn_mfma_f32_16x16x32_bf16(a0, b0, acc[nt], 0, 0, 0);
    acc[nt] = __builtin_amdgcn_mfma_f32_16x16x32_bf16(a1, b1, acc[nt], 0, 0, 0);
  }
}

__device__ __forceinline__ void binit(f32x4 acc[4], float x, float y, float z, float w) {
  f32x4 v; v[0] = x; v[1] = y; v[2] = z; v[3] = w;
#pragma unroll
  for (int nt = 0; nt < 4; ++nt) acc[nt] = v;
}

__global__ void diag_kernel(float* out, float v) { out[0] = v; }

// ---------- prep: weight 64x64 slices -> fragment-ordered bf16 (34 slices) ----------
__global__ __launch_bounds__(256) void prep_kernel(
    const float* __restrict__ enc_w2, const float* __restrict__ head_w1,
    const float* __restrict__ l_w1, const float* __restrict__ l_w2,
    const float* __restrict__ l_gwih, const float* __restrict__ l_gwhh,
    ushort* __restrict__ gwF) {
  const int id = blockIdx.x;
  const int t = threadIdx.x;
  const float* src;
  int ld = 64;
  if (id == 0)      { src = enc_w2; }
  else if (id == 1) { src = head_w1; ld = 128; }
  else if (id < 6)  { src = l_w1 + (id - 2) * 4096; }
  else if (id < 10) { src = l_w2 + (id - 6) * 4096; }
  else if (id < 22) { int q = id - 10; src = l_gwih + (q / 3) * 12288 + (q % 3) * 4096; }
  else              { int q = id - 22; src = l_gwhh + (q / 3) * 12288 + (q % 3) * 4096; }
  uint4* dst = (uint4*)(gwF + (size_t)id * 4096);
#pragma unroll
  for (int i = 0; i < 2; ++i) {
    int ch = i * 256 + t;
    int q = ch & 63;
    int g = ch >> 6;
    int j = (g >> 1) * 16 + (q & 15);
    int k = (g & 1) * 32 + (q >> 4) * 8;
    const float* s = src + (size_t)j * ld + k;
    float4 f0 = *(const float4*)(s);
    float4 f1 = *(const float4*)(s + 4);
    uint4 o;
    o.x = pk2(f0.x, f0.y); o.y = pk2(f0.z, f0.w);
    o.z = pk2(f1.x, f1.y); o.w = pk2(f1.z, f1.w);
    dst[ch] = o;
  }
}

// ---------- encoder: 128 nodes / 512 threads; writes xG + duplicated row-max partials ----------
// LDS: P@0 (16K), W1s@16384 (1K), REDm@17408 (512B)
__global__ __launch_bounds__(512) void encoder_kernel(
    const float4* __restrict__ hyb, ushort* __restrict__ xG,
    const ushort* __restrict__ gwF, const float* __restrict__ enc_w1,
    const float* __restrict__ b1, const float* __restrict__ gg,
    const float* __restrict__ be, const float* __restrict__ b2,
    float* __restrict__ rmOut) {
  __shared__ __align__(16) unsigned char L[17920];
  const int t = threadIdx.x;
  const int w = t >> 6, l = t & 63, lq = l >> 4, lr = l & 15;
  const int ws = w & 3, nh = w >> 2;
  const int gbase = blockIdx.x * 128;
  const int j0 = ws * 16 + lq * 4;

  if (t < 256) ((float*)(L + 16384))[t] = enc_w1[t];
  __syncthreads();

  { // GEMM1 (K=4, VALU) + LN + ReLU -> P[n][j] swizzled bf16
    const int n = t >> 2, part = t & 3;
    float4 iv = hyb[gbase + n];
    const float* W1 = (const float*)(L + 16384);
    float h[16];
#pragma unroll
    for (int jj = 0; jj < 16; ++jj) {
      int j = part * 16 + jj;
      float4 wr = *(const float4*)(W1 + j * 4);
      h[jj] = b1[j] + wr.x * iv.x + wr.y * iv.y + wr.z * iv.z + wr.w * iv.w;
    }
    float s = 0.f, q = 0.f;
#pragma unroll
    for (int jj = 0; jj < 16; ++jj) { s += h[jj]; q += h[jj] * h[jj]; }
    s += __shfl_xor(s, 1); q += __shfl_xor(q, 1);
    s += __shfl_xor(s, 2); q += __shfl_xor(q, 2);
    float mean = s * (1.f / 64.f);
    float rstd = rsqrtf(q * (1.f / 64.f) - mean * mean + 1e-5f);
    u32 pk[8];
#pragma unroll
    for (int jj = 0; jj < 16; jj += 2) {
      int j = part * 16 + jj;
      float v0 = relu((h[jj] - mean) * rstd * gg[j] + be[j]);
      float v1 = relu((h[jj + 1] - mean) * rstd * gg[j + 1] + be[j + 1]);
      pk[jj >> 1] = pk2(v0, v1);
    }
    *(uint4*)(L + n * 128 + SWZ(n, part * 32))      = make_uint4(pk[0], pk[1], pk[2], pk[3]);
    *(uint4*)(L + n * 128 + SWZ(n, part * 32 + 16)) = make_uint4(pk[4], pk[5], pk[6], pk[7]);
  }
  __syncthreads();

  float4 vb2 = *(const float4*)(b2 + j0);
  f32x4 acc[4];
  binit(acc, vb2.x, vb2.y, vb2.z, vb2.w);
  { // gemm from LDS P (512-thread variant: node-half nh)
    s16x8 a0 = *(const s16x8*)(gwF + ((ws * 128 + l) << 3));
    s16x8 a1 = *(const s16x8*)(gwF + ((ws * 128 + 64 + l) << 3));
    const int c0 = (lq << 4) ^ ((lr & 7) << 4);
    const unsigned char* Bp = L + nh * 8192 + lr * 128;
#pragma unroll
    for (int nt = 0; nt < 4; ++nt) {
      s16x8 b0 = *(const s16x8*)(Bp + nt * 2048 + c0);
      s16x8 b1 = *(const s16x8*)(Bp + nt * 2048 + (c0 ^ 64));
      acc[nt] = __builtin_amdgcn_mfma_f32_16x16x32_bf16(a0, b0, acc[nt], 0, 0, 0);
      acc[nt] = __builtin_amdgcn_mfma_f32_16x16x32_bf16(a1, b1, acc[nt], 0, 0, 0);
    }
  }
  // direct register->global epilogue
  {
    ushort* xout = xG + (size_t)gbase * 64;
#pragma unroll
    for (int nt = 0; nt < 4; ++nt) {
      int n = nh * 64 + nt * 16 + lr;
      *(uint2*)(xout + (size_t)n * 64 + j0) =
          make_uint2(pk2(acc[nt][0], acc[nt][1]), pk2(acc[nt][2], acc[nt][3]));
    }
  }
  { // row-max partial
    float mt[4];
#pragma unroll
    for (int r = 0; r < 4; ++r)
      mt[r] = fmaxf(fmaxf(acc[0][r], acc[1][r]), fmaxf(acc[2][r], acc[3][r]));
#pragma unroll
    for (int m = 1; m < 16; m <<= 1)
#pragma unroll
      for (int r = 0; r < 4; ++r) mt[r] = fmaxf(mt[r], __shfl_xor(mt[r], m));
    if (lr == 0) {
      float4 v; v.x = mt[0]; v.y = mt[1]; v.z = mt[2]; v.w = mt[3];
      *(float4*)(L + 17408 + (nh * 64 + j0) * 4) = v;
    }
  }
  __syncthreads();
  if (t < 64) {
    const float* R = (const float*)(L + 17408);
    float v = fmaxf(R[t], R[64 + t]);
    rmOut[(size_t)(blockIdx.x * 2 + 0) * 64 + t] = v;   // duplicated partials so all
    rmOut[(size_t)(blockIdx.x * 2 + 1) * 64 + t] = v;   // consumers fmax a pair
  }
}

// ---------- fused pass: 64 nodes / 256 threads, x-tile held in registers ----------
// LDS: P@0 (8K), U@8192 (8K), RED@16384 (2K) = 18432 B
#define PP  0
#define PU  8192
#define PRED 16384

__global__ __launch_bounds__(256, 4) void pass_kernel(
    ushort* __restrict__ xG, const ushort* __restrict__ gwF,
    const float* __restrict__ rmP, const ushort* __restrict__ cmB, int mode,
    int s_w1, int s_w2, int s_ih0, int s_hh0,
    const float* __restrict__ b1, const float* __restrict__ b2,
    const float* __restrict__ gg, const float* __restrict__ be,
    const float* __restrict__ bih, const float* __restrict__ bhh,
    float* __restrict__ rmOut) {
  __shared__ __align__(16) unsigned char L[18432];
  const int t = threadIdx.x;
  const int ws = t >> 6, l = t & 63, lq = l >> 4, lr = l & 15;
  const int gbase = blockIdx.x * 64;
  const int j0 = ws * 16 + lq * 4;
  const int colb = ws * 32 + lq * 8;
  const int rowp = (gbase >> 7) * 2;            // first partial slot of this row
  const int b = gbase >> 15;
  const int k1b = gbase & 127;

  const ushort* Aw1 = gwF + (size_t)s_w1 * 4096;
  const ushort* Aw2 = gwF + (size_t)s_w2 * 4096;
  const ushort* Ai0 = gwF + (size_t)s_ih0 * 4096;
  const ushort* Ai1 = Ai0 + 4096;
  const ushort* Ai2 = Ai1 + 4096;
  const ushort* Ah0 = gwF + (size_t)s_hh0 * 4096;
  const ushort* Ah1 = Ah0 + 4096;
  const ushort* Ah2 = Ah1 + 4096;

  // x-tile B-fragments straight from global (node-major xG IS fragment layout):
  // fragment (nt,kb) = features [lq*8+kb*32 .. +8) of node gbase+nt*16+lr.
  s16x8 bx[8];
  {
    const ushort* xp = xG + ((size_t)(gbase + lr)) * 64 + lq * 8;
#pragma unroll
    for (int nt = 0; nt < 4; ++nt) {
      bx[nt * 2 + 0] = *(const s16x8*)(xp + nt * 1024);
      bx[nt * 2 + 1] = *(const s16x8*)(xp + nt * 1024 + 32);
    }
  }

  // GEMM1: h1 = W1*x + W1*(-mv) + b1  (no LDS, no barrier needed first)
  f32x4 acc[4];
  {
    float4 vb1 = *(const float4*)(b1 + j0);
    if (mode == 0) {
      // row-max is node-uniform -> 2 MFMA compute dmv, folded into the bias
      float m0[8], m1[8];
      const float* r0 = rmP + (size_t)rowp * 64;
#pragma unroll
      for (int q = 0; q < 8; ++q) {
        m0[q] = -fmaxf(r0[lq * 8 + q], r0[64 + lq * 8 + q]);
        m1[q] = -fmaxf(r0[32 + lq * 8 + q], r0[96 + lq * 8 + q]);
      }
      s16x8 bmv0 = pack8(m0), bmv1 = pack8(m1);
      s16x8 a0 = *(const s16x8*)(Aw1 + ((ws * 128 + l) << 3));
      s16x8 a1 = *(const s16x8*)(Aw1 + ((ws * 128 + 64 + l) << 3));
      f32x4 dmv; dmv[0] = 0.f; dmv[1] = 0.f; dmv[2] = 0.f; dmv[3] = 0.f;
      dmv = __builtin_amdgcn_mfma_f32_16x16x32_bf16(a0, bmv0, dmv, 0, 0, 0);
      dmv = __builtin_amdgcn_mfma_f32_16x16x32_bf16(a1, bmv1, dmv, 0, 0, 0);
#pragma unroll
      for (int nt = 0; nt < 4; ++nt) {
        acc[nt][0] = vb1.x + dmv[0]; acc[nt][1] = vb1.y + dmv[1];
        acc[nt][2] = vb1.z + dmv[2]; acc[nt][3] = vb1.w + dmv[3];
      }
    } else {
      binit(acc, vb1.x, vb1.y, vb1.z, vb1.w);
      s16x8 bmv[8];   // pre-negated bf16 colmax fragments, straight from global
      const ushort* cp = cmB + ((size_t)(b * 128 + k1b + lr)) * 64 + lq * 8;
#pragma unroll
      for (int nt = 0; nt < 4; ++nt) {
        bmv[nt * 2 + 0] = *(const s16x8*)(cp + nt * 1024);
        bmv[nt * 2 + 1] = *(const s16x8*)(cp + nt * 1024 + 32);
      }
      gemmR(Aw1, bmv, ws, l, acc);
    }
  }
  gemmR(Aw1, bx, ws, l, acc);
#pragma unroll
  for (int nt = 0; nt < 4; ++nt) {
    float s = acc[nt][0] + acc[nt][1] + acc[nt][2] + acc[nt][3];
    float q = acc[nt][0] * acc[nt][0] + acc[nt][1] * acc[nt][1] +
              acc[nt][2] * acc[nt][2] + acc[nt][3] * acc[nt][3];
    s += __shfl_xor(s, 16); q += __shfl_xor(q, 16);
    s += __shfl_xor(s, 32); q += __shfl_xor(q, 32);
    if (lq == 0)
      *(float2*)(L + PRED + (ws * 64 + nt * 16 + lr) * 8) = make_float2(s, q);
  }
  __syncthreads();                                   // B1
  { // LN + ReLU -> P (h)
    float4 vg = *(const float4*)(gg + j0);
    float4 vbe = *(const float4*)(be + j0);
    float gv[4] = {vg.x, vg.y, vg.z, vg.w};
    float bv[4] = {vbe.x, vbe.y, vbe.z, vbe.w};
#pragma unroll
    for (int nt = 0; nt < 4; ++nt) {
      int np = nt * 16 + lr;
      float ss = 0.f, qq = 0.f;
#pragma unroll
      for (int wv = 0; wv < 4; ++wv) {
        float2 pr = *(const float2*)(L + PRED + (wv * 64 + np) * 8);
        ss += pr.x; qq += pr.y;
      }
      float mean = ss * (1.f / 64.f);
      float rstd = rsqrtf(qq * (1.f / 64.f) - mean * mean + 1e-5f);
      float h_[4];
#pragma unroll
      for (int r = 0; r < 4; ++r) h_[r] = relu((acc[nt][r] - mean) * rstd * gv[r] + bv[r]);
      *(uint2*)(L + PP + np * 128 + SWZ(np, colb)) =
          make_uint2(pk2(h_[0], h_[1]), pk2(h_[2], h_[3]));
    }
  }
  __syncthreads();                                   // B2
  __builtin_amdgcn_sched_barrier(0);                 // fence: no A-load hoist above

  // GEMM2: u = W2 * h + b2 ; write u -> U
  { float4 v = *(const float4*)(b2 + j0); binit(acc, v.x, v.y, v.z, v.w); }
  gemmG(Aw2, L, PP, ws, l, lq, lr, acc);
#pragma unroll
  for (int nt = 0; nt < 4; ++nt) {
    int n = nt * 16 + lr;
    *(uint2*)(L + PU + n * 128 + SWZ(n, colb)) =
        make_uint2(pk2(acc[nt][0], acc[nt][1]), pk2(acc[nt][2], acc[nt][3]));
  }
  __builtin_amdgcn_sched_barrier(0);                 // fence

  // ah = bh_n + Whh_n * x  (bx in regs -> overlaps other waves' U writes)
  f32x4 ah[4];
  { float4 v = *(const float4*)(bhh + 128 + j0); binit(ah, v.x, v.y, v.z, v.w); }
  gemmR(Ah2, bx, ws, l, ah);
  __syncthreads();                                   // B3: U published
  __builtin_amdgcn_sched_barrier(0);                 // fence

  f32x4 ar[4];                                       // r = sigm(Wih_r*u + Whh_r*x + b)
  { float4 vi = *(const float4*)(bih + j0);
    float4 vh = *(const float4*)(bhh + j0);
    binit(ar, vi.x + vh.x, vi.y + vh.y, vi.z + vh.z, vi.w + vh.w); }
  gemmG(Ai0, L, PU, ws, l, lq, lr, ar);
  gemmR(Ah0, bx, ws, l, ar);
  __builtin_amdgcn_sched_barrier(0);                 // fence

  f32x4 an[4];                                       // an = bi_n + r*ah; += Wih_n*u
  { float4 v = *(const float4*)(bih + 128 + j0);
    float bv[4] = {v.x, v.y, v.z, v.w};
#pragma unroll
    for (int nt = 0; nt < 4; ++nt)
#pragma unroll
      for (int r = 0; r < 4; ++r)
        an[nt][r] = bv[r] + sigm(ar[nt][r]) * ah[nt][r];
  }
  gemmG(Ai2, L, PU, ws, l, lq, lr, an);
  __builtin_amdgcn_sched_barrier(0);                 // fence

  f32x4 az[4];                                       // z gate
  { float4 vi = *(const float4*)(bih + 64 + j0);
    float4 vh = *(const float4*)(bhh + 64 + j0);
    binit(az, vi.x + vh.x, vi.y + vh.y, vi.z + vh.z, vi.w + vh.w); }
  gemmG(Ai1, L, PU, ws, l, lq, lr, az);
  gemmR(Ah1, bx, ws, l, az);

  // epilogue: xn from registers; x re-read from global (L2-hot), direct stores
  float xn[4][4];
#pragma unroll
  for (int nt = 0; nt < 4; ++nt) {
    int n = nt * 16 + lr;
    uint2 xo = *(const uint2*)(xG + ((size_t)(gbase + n)) * 64 + j0);
    float xv[4] = {bflo(xo.x), bfhi(xo.x), bflo(xo.y), bfhi(xo.y)};
#pragma unroll
    for (int r = 0; r < 4; ++r) {
      float nn = tanh_f(an[nt][r]);
      float zz = sigm(az[nt][r]);
      xn[nt][r] = nn + zz * (xv[r] - nn);
    }
  }
  {
    ushort* xout = xG + (size_t)gbase * 64;
#pragma unroll
    for (int nt = 0; nt < 4; ++nt) {
      int n = nt * 16 + lr;
      *(uint2*)(xout + (size_t)n * 64 + j0) =
          make_uint2(pk2(xn[nt][0], xn[nt][1]), pk2(xn[nt][2], xn[nt][3]));
    }
  }
  { // row-max partial over this block's 64 nodes
    float mt[4];
#pragma unroll
    for (int r = 0; r < 4; ++r)
      mt[r] = fmaxf(fmaxf(xn[0][r], xn[1][r]), fmaxf(xn[2][r], xn[3][r]));
#pragma unroll
    for (int m = 1; m < 16; m <<= 1)
#pragma unroll
      for (int r = 0; r < 4; ++r) mt[r] = fmaxf(mt[r], __shfl_xor(mt[r], m));
    if (lr == 0) {
      float4 v; v.x = mt[0]; v.y = mt[1]; v.z = mt[2]; v.w = mt[3];
      *(float4*)(rmOut + (size_t)blockIdx.x * 64 + j0) = v;
    }
  }
}

// ---------- colmax: cmB[b][k1][k] = NEGATED bf16 max over 256 m (MFMA-B-ready) ----------
__global__ __launch_bounds__(256) void colmax_kernel(const ushort* __restrict__ xG,
                                                     ushort* __restrict__ cmB) {
  const int t = threadIdx.x;
  const int b = blockIdx.x >> 4, kg = blockIdx.x & 15;
  const int col = t & 31, k1 = kg * 8 + (t >> 5);
  const u32* xu = (const u32*)xG;
  float m0 = -INFINITY, m1 = -INFINITY;
  for (int m = 0; m < 256; ++m) {
    size_t node = ((size_t)(b * 256 + m)) * 128 + k1;
    u32 v = xu[node * 32 + col];
    m0 = fmaxf(m0, bflo(v)); m1 = fmaxf(m1, bfhi(v));
  }
  ((u32*)cmB)[((size_t)(b * 128 + k1)) * 32 + col] = pk2(-m0, -m1);
}

// ---------- top-level GRU (folds global max from 512 partials per b) ----------
__global__ __launch_bounds__(64) void topgru_kernel(
    const float* __restrict__ rm, const float* __restrict__ hs,
    const float* __restrict__ gwih, const float* __restrict__ gwhh,
    const float* __restrict__ gbih, const float* __restrict__ gbhh,
    float* __restrict__ nh, float* __restrict__ outTail) {
  __shared__ float gf[64], h0[64];
  const int b = blockIdx.x, j = threadIdx.x;
  float g0 = -INFINITY, g1 = -INFINITY, g2 = -INFINITY, g3 = -INFINITY;
  const float* base = rm + (size_t)b * 512 * 64 + j;
  for (int r = 0; r < 512; r += 4) {
    g0 = fmaxf(g0, base[(r + 0) * 64]);
    g1 = fmaxf(g1, base[(r + 1) * 64]);
    g2 = fmaxf(g2, base[(r + 2) * 64]);
    g3 = fmaxf(g3, base[(r + 3) * 64]);
  }
  gf[j] = fmaxf(fmaxf(g0, g1), fmaxf(g2, g3));
  h0[j] = hs[b * 64 + j];
  __syncthreads();
  float gi[3], gh[3];
#pragma unroll
  for (int g = 0; g < 3; ++g) {
    float s = gbih[g * 64 + j];
    const float* wr = gwih + (g * 64 + j) * 64;
    for (int k = 0; k < 64; ++k) s += wr[k] * gf[k];
    gi[g] = s;
  }
#pragma unroll
  for (int g = 0; g < 3; ++g) {
    float s = gbhh[g * 64 + j];
    const float* wr = gwhh + (g * 64 + j) * 64;
    for (int k = 0; k < 64; ++k) s += wr[k] * h0[k];
    gh[g] = s;
  }
  float rr = sigm(gi[0] + gh[0]);
  float zz = sigm(gi[1] + gh[1]);
  float nn = tanh_f(gi[2] + rr * gh[2]);
  float val = (1.0f - zz) * nn + zz * h0[j];
  nh[b * 64 + j] = val;
  outTail[b * 64 + j] = val;
}

// ---------- head constant: hc[b][j] = head_b1[j] + head_w1[j,64:] @ nh[b] ----------
__global__ __launch_bounds__(64) void hc_kernel(const float* __restrict__ nh,
                                                const float* __restrict__ hw1,
                                                const float* __restrict__ hb1,
                                                float* __restrict__ hc) {
  __shared__ float h0[64];
  const int b = blockIdx.x, j = threadIdx.x;
  h0[j] = nh[b * 64 + j];
  __syncthreads();
  float s = hb1[j];
  const float* wr = hw1 + j * 128 + 64;
  for (int k = 0; k < 64; ++k) s += wr[k] * h0[k];
  hc[b * 64 + j] = s;
}

// ---------- head: logits (128 nodes / 512 threads, x fragments from global) ----------
__global__ __launch_bounds__(512) void head_kernel(
    const ushort* __restrict__ xG, const ushort* __restrict__ gwF,
    const float* __restrict__ hc, const float* __restrict__ hw2,
    const float* __restrict__ hb2, float* __restrict__ out) {
  __shared__ float RED[512];
  const int t = threadIdx.x;
  const int w = t >> 6, l = t & 63, lq = l >> 4, lr = l & 15;
  const int ws = w & 3, nh = w >> 2;
  const int gbase = blockIdx.x * 128;
  const int b = gbase >> 15;
  const int j0 = ws * 16 + lq * 4;

  s16x8 bh[8];
  {
    const ushort* xp = xG + ((size_t)(gbase + nh * 64 + lr)) * 64 + lq * 8;
#pragma unroll
    for (int nt = 0; nt < 4; ++nt) {
      bh[nt * 2 + 0] = *(const s16x8*)(xp + nt * 1024);
      bh[nt * 2 + 1] = *(const s16x8*)(xp + nt * 1024 + 32);
    }
  }
  float4 vhc = *(const float4*)(hc + b * 64 + j0);
  f32x4 acc[4];
  binit(acc, vhc.x, vhc.y, vhc.z, vhc.w);
  gemmR(gwF + 4096, bh, ws, l, acc);   // slice 1 = head_w1[:, :64]

  float4 w2v = *(const float4*)(hw2 + j0);
  float w2a[4] = {w2v.x, w2v.y, w2v.z, w2v.w};
#pragma unroll
  for (int nt = 0; nt < 4; ++nt) {
    float p = 0.f;
#pragma unroll
    for (int r = 0; r < 4; ++r) p += w2a[r] * relu(acc[nt][r]);
    p += __shfl_xor(p, 16);
    p += __shfl_xor(p, 32);
    if (lq == 0) RED[(nh * 4 + ws) * 64 + nt * 16 + lr] = p;
  }
  __syncthreads();
  if (t < 128) {
    const float* red = RED + (t >> 6) * 256 + (t & 63);
    out[gbase + t] = red[0] + red[64] + red[128] + red[192] + hb2[0];
  }
}

// ---------- host ----------
extern "C" void kernel_launch(void* const* d_in, const int* in_sizes, int n_in,
                              void* d_out, int out_size, void* d_ws, size_t ws_size,
                              hipStream_t stream) {
  const float* hybrid   = (const float*)d_in[0];
  const float* hidden   = (const float*)d_in[1];
  const float* enc_w1   = (const float*)d_in[2];
  const float* enc_b1   = (const float*)d_in[3];
  const float* enc_g    = (const float*)d_in[4];
  const float* enc_beta = (const float*)d_in[5];
  const float* enc_w2   = (const float*)d_in[6];
  const float* enc_b2   = (const float*)d_in[7];
  const float* l_w1     = (const float*)d_in[8];
  const float* l_b1     = (const float*)d_in[9];
  const float* l_g      = (const float*)d_in[10];
  const float* l_beta   = (const float*)d_in[11];
  const float* l_w2     = (const float*)d_in[12];
  const float* l_b2     = (const float*)d_in[13];
  const float* l_gwih   = (const float*)d_in[14];
  const float* l_gwhh   = (const float*)d_in[15];
  const float* l_gbih   = (const float*)d_in[16];
  const float* l_gbhh   = (const float*)d_in[17];
  const float* g_wih    = (const float*)d_in[18];
  const float* g_whh    = (const float*)d_in[19];
  const float* g_bih    = (const float*)d_in[20];
  const float* g_bhh    = (const float*)d_in[21];
  const float* head_w1  = (const float*)d_in[22];
  const float* head_b1  = (const float*)d_in[23];
  const float* head_w2  = (const float*)d_in[24];
  const float* head_b2  = (const float*)d_in[25];

  char* p = (char*)d_ws;
  size_t off = 0;
  auto carve = [&](size_t bytes) { void* r = p + off; off = (off + bytes + 255) & ~255ULL; return r; };
  ushort* xG  = (ushort*)carve((size_t)NTOT * 64 * 2);     // 128 MiB node-major bf16
  ushort* gwF = (ushort*)carve(34 * 4096 * 2);
  float*  rmA = (float*)carve((size_t)16384 * 64 * 4);     // row-max partials (dbuf A)
  float*  rmB = (float*)carve((size_t)16384 * 64 * 4);     // row-max partials (dbuf B)
  ushort* cmB = (ushort*)carve((size_t)32 * 128 * 64 * 2); // NEGATED bf16 colmax tiles
  float*  nh  = (float*)carve(2048 * 4);
  float*  hcb = (float*)carve(2048 * 4);

  if (ws_size < off) {
    diag_kernel<<<1, 1, 0, stream>>>((float*)d_out, 1.0f + (float)ws_size * 1e-9f);
    return;
  }

  prep_kernel<<<34, 256, 0, stream>>>(enc_w2, head_w1, l_w1, l_w2, l_gwih, l_gwhh, gwF);
  encoder_kernel<<<8192, 512, 0, stream>>>((const float4*)hybrid, xG, gwF, enc_w1,
                                           enc_b1, enc_g, enc_beta, enc_b2, rmA);

  // rm double-buffer: pass reads rmRead, writes rmWrite (avoids intra-kernel races)
  float* rmRead = rmA;
  float* rmWrite = rmB;
  for (int lyr = 0; lyr < 2; ++lyr) {
    for (int s = 0; s < 2; ++s) {
      const int m = lyr * 2 + s;
      if (s == 1) colmax_kernel<<<512, 256, 0, stream>>>(xG, cmB);
      pass_kernel<<<16384, 256, 0, stream>>>(
          xG, gwF, rmRead, cmB, s,
          2 + m, 6 + m, 10 + 3 * m, 22 + 3 * m,
          l_b1 + m * 64, l_b2 + m * 64, l_g + m * 64, l_beta + m * 64,
          l_gbih + m * 192, l_gbhh + m * 192, rmWrite);
      float* tmp = rmRead; rmRead = rmWrite; rmWrite = tmp;
    }
  }

  topgru_kernel<<<32, 64, 0, stream>>>(rmRead, hidden, g_wih, g_whh, g_bih, g_bhh,
                                       nh, (float*)d_out + 1048576);
  hc_kernel<<<32, 64, 0, stream>>>(nh, head_w1, head_b1, hcb);
  head_kernel<<<8192, 512, 0, stream>>>(xG, gwF, hcb, head_w2, head_b2, (float*)d_out);
}

// Round 12
// 748.476 us; speedup vs baseline: 1.3416x; 1.3416x over previous
//
#include <hip/hip_runtime.h>
#include <math.h>

typedef unsigned int u32;
typedef unsigned short u16;
typedef __attribute__((ext_vector_type(4))) float f32x4;
typedef __attribute__((ext_vector_type(8))) short s16x8;

#define NTOT 1048576
#define SWZ(n, col) ((col) ^ (((n) & 7) << 4))

__device__ __forceinline__ float bflo(u32 v) { return __uint_as_float(v << 16); }
__device__ __forceinline__ float bfhi(u32 v) { return __uint_as_float(v & 0xffff0000u); }
// RTNE f32->bf16 pair pack: bit-identical to the R3 manual sequence, final
// select is one v_perm_b32. Do NOT use v_cvt_pk_bf16_f32 (non-RNE -> R4 fail).
__device__ __forceinline__ u32 rndbf(float f) {
  u32 u = __float_as_uint(f);
  return u + 0x7fffu + ((u >> 16) & 1u);
}
__device__ __forceinline__ u32 pk2(float a, float b) {
  return __builtin_amdgcn_perm(rndbf(b), rndbf(a), 0x07060302u);
}
__device__ __forceinline__ float sigm(float x) {
  return __builtin_amdgcn_rcpf(1.0f + __expf(-x));
}
__device__ __forceinline__ float tanh_f(float x) {
  float e = __expf(2.0f * x);
  return 1.0f - 2.0f * __builtin_amdgcn_rcpf(e + 1.0f);
}
__device__ __forceinline__ float relu(float x) { return fmaxf(x, 0.0f); }

// ---------- MFMA 64x64 GEMM micro-kernel (256-thread: wave ws owns j-slice, all 64 nodes)
// A: fragment-ordered weights from GLOBAL (L2-resident); B from LDS (swizzled).
// This split is deliberate (R11 lesson): A rides VMEM, B rides LDS -> the two
// operand streams overlap; all-global B serializes on VMEM latency.
// sched_barrier(0) fences between gates stop the all-gates A-load hoist
// (R6/R7 scratch spill).
__device__ __forceinline__ void gemmG(const ushort* __restrict__ gA,
                                      const unsigned char* L, int boff,
                                      int ws, int l, int lq, int lr,
                                      f32x4 acc[4]) {
  s16x8 a0 = *(const s16x8*)(gA + ((ws * 128 + l) << 3));
  s16x8 a1 = *(const s16x8*)(gA + ((ws * 128 + 64 + l) << 3));
  const int c0 = (lq << 4) ^ ((lr & 7) << 4);
  const unsigned char* Bp = L + boff + lr * 128;
#pragma unroll
  for (int nt = 0; nt < 4; ++nt) {
    s16x8 b0 = *(const s16x8*)(Bp + nt * 2048 + c0);
    s16x8 b1 = *(const s16x8*)(Bp + nt * 2048 + (c0 ^ 64));
    acc[nt] = __builtin_amdgcn_mfma_f32_16x16x32_bf16(a0, b0, acc[nt], 0, 0, 0);
    acc[nt] = __builtin_amdgcn_mfma_f32_16x16x32_bf16(a1, b1, acc[nt], 0, 0, 0);
  }
}

// 512-thread variant (wave (ws,nh): j-slice ws, node-half nh) for encoder/head
__device__ __forceinline__ void gemmG2(const ushort* __restrict__ gA,
                                       const unsigned char* L, int boff,
                                       int ws, int nh, int l, int lq, int lr,
                                       f32x4 acc[4]) {
  s16x8 a0 = *(const s16x8*)(gA + ((ws * 128 + l) << 3));
  s16x8 a1 = *(const s16x8*)(gA + ((ws * 128 + 64 + l) << 3));
  const int c0 = (lq << 4) ^ ((lr & 7) << 4);
  const unsigned char* Bp = L + boff + nh * 8192 + lr * 128;
#pragma unroll
  for (int nt = 0; nt < 4; ++nt) {
    s16x8 b0 = *(const s16x8*)(Bp + nt * 2048 + c0);
    s16x8 b1 = *(const s16x8*)(Bp + nt * 2048 + (c0 ^ 64));
    acc[nt] = __builtin_amdgcn_mfma_f32_16x16x32_bf16(a0, b0, acc[nt], 0, 0, 0);
    acc[nt] = __builtin_amdgcn_mfma_f32_16x16x32_bf16(a1, b1, acc[nt], 0, 0, 0);
  }
}

__device__ __forceinline__ void binit(f32x4 acc[4], float x, float y, float z, float w) {
  f32x4 v; v[0] = x; v[1] = y; v[2] = z; v[3] = w;
#pragma unroll
  for (int nt = 0; nt < 4; ++nt) acc[nt] = v;
}

__global__ void diag_kernel(float* out, float v) { out[0] = v; }

// ---------- prep: weight 64x64 slices -> fragment-ordered bf16 (34 slices) ----------
__global__ __launch_bounds__(256) void prep_kernel(
    const float* __restrict__ enc_w2, const float* __restrict__ head_w1,
    const float* __restrict__ l_w1, const float* __restrict__ l_w2,
    const float* __restrict__ l_gwih, const float* __restrict__ l_gwhh,
    ushort* __restrict__ gwF) {
  const int id = blockIdx.x;
  const int t = threadIdx.x;
  const float* src;
  int ld = 64;
  if (id == 0)      { src = enc_w2; }
  else if (id == 1) { src = head_w1; ld = 128; }
  else if (id < 6)  { src = l_w1 + (id - 2) * 4096; }
  else if (id < 10) { src = l_w2 + (id - 6) * 4096; }
  else if (id < 22) { int q = id - 10; src = l_gwih + (q / 3) * 12288 + (q % 3) * 4096; }
  else              { int q = id - 22; src = l_gwhh + (q / 3) * 12288 + (q % 3) * 4096; }
  uint4* dst = (uint4*)(gwF + (size_t)id * 4096);
#pragma unroll
  for (int i = 0; i < 2; ++i) {
    int ch = i * 256 + t;
    int q = ch & 63;
    int g = ch >> 6;
    int j = (g >> 1) * 16 + (q & 15);
    int k = (g & 1) * 32 + (q >> 4) * 8;
    const float* s = src + (size_t)j * ld + k;
    float4 f0 = *(const float4*)(s);
    float4 f1 = *(const float4*)(s + 4);
    uint4 o;
    o.x = pk2(f0.x, f0.y); o.y = pk2(f0.z, f0.w);
    o.z = pk2(f1.x, f1.y); o.w = pk2(f1.z, f1.w);
    dst[ch] = o;
  }
}

// ---------- encoder: 128 nodes / 512 threads; writes xG + duplicated row-max partials ----------
// LDS: P@0 (16K), XL@16384 (16K), W1s@32768 (1K), REDm@33792 (512B)
__global__ __launch_bounds__(512) void encoder_kernel(
    const float4* __restrict__ hyb, ushort* __restrict__ xG,
    const ushort* __restrict__ gwF, const float* __restrict__ enc_w1,
    const float* __restrict__ b1, const float* __restrict__ gg,
    const float* __restrict__ be, const float* __restrict__ b2,
    float* __restrict__ rmOut) {
  __shared__ __align__(16) unsigned char L[34304];
  const int t = threadIdx.x;
  const int w = t >> 6, l = t & 63, lq = l >> 4, lr = l & 15;
  const int ws = w & 3, nh = w >> 2;
  const int gbase = blockIdx.x * 128;
  const int j0 = ws * 16 + lq * 4;
  const int colb = ws * 32 + lq * 8;

  if (t < 256) ((float*)(L + 32768))[t] = enc_w1[t];
  __syncthreads();

  { // GEMM1 (K=4, VALU) + LN + ReLU -> P[n][j] swizzled bf16
    const int n = t >> 2, part = t & 3;
    float4 iv = hyb[gbase + n];
    const float* W1 = (const float*)(L + 32768);
    float h[16];
#pragma unroll
    for (int jj = 0; jj < 16; ++jj) {
      int j = part * 16 + jj;
      float4 wr = *(const float4*)(W1 + j * 4);
      h[jj] = b1[j] + wr.x * iv.x + wr.y * iv.y + wr.z * iv.z + wr.w * iv.w;
    }
    float s = 0.f, q = 0.f;
#pragma unroll
    for (int jj = 0; jj < 16; ++jj) { s += h[jj]; q += h[jj] * h[jj]; }
    s += __shfl_xor(s, 1); q += __shfl_xor(q, 1);
    s += __shfl_xor(s, 2); q += __shfl_xor(q, 2);
    float mean = s * (1.f / 64.f);
    float rstd = rsqrtf(q * (1.f / 64.f) - mean * mean + 1e-5f);
    u32 pk[8];
#pragma unroll
    for (int jj = 0; jj < 16; jj += 2) {
      int j = part * 16 + jj;
      float v0 = relu((h[jj] - mean) * rstd * gg[j] + be[j]);
      float v1 = relu((h[jj + 1] - mean) * rstd * gg[j + 1] + be[j + 1]);
      pk[jj >> 1] = pk2(v0, v1);
    }
    *(uint4*)(L + n * 128 + SWZ(n, part * 32))      = make_uint4(pk[0], pk[1], pk[2], pk[3]);
    *(uint4*)(L + n * 128 + SWZ(n, part * 32 + 16)) = make_uint4(pk[4], pk[5], pk[6], pk[7]);
  }
  __syncthreads();

  float4 vb2 = *(const float4*)(b2 + j0);
  f32x4 acc[4];
  binit(acc, vb2.x, vb2.y, vb2.z, vb2.w);
  gemmG2(gwF, L, 0, ws, nh, l, lq, lr, acc);          // slice 0 = enc_w2
#pragma unroll
  for (int nt = 0; nt < 4; ++nt) {
    int n = nh * 64 + nt * 16 + lr;
    *(uint2*)(L + 16384 + n * 128 + SWZ(n, colb)) =
        make_uint2(pk2(acc[nt][0], acc[nt][1]), pk2(acc[nt][2], acc[nt][3]));
  }
  { // row-max partial
    float mt[4];
#pragma unroll
    for (int r = 0; r < 4; ++r)
      mt[r] = fmaxf(fmaxf(acc[0][r], acc[1][r]), fmaxf(acc[2][r], acc[3][r]));
#pragma unroll
    for (int m = 1; m < 16; m <<= 1)
#pragma unroll
      for (int r = 0; r < 4; ++r) mt[r] = fmaxf(mt[r], __shfl_xor(mt[r], m));
    if (lr == 0) {
      float4 v; v.x = mt[0]; v.y = mt[1]; v.z = mt[2]; v.w = mt[3];
      *(float4*)(L + 33792 + (nh * 64 + j0) * 4) = v;
    }
  }
  __syncthreads();
  {
    uint4* xout = (uint4*)(xG + (size_t)gbase * 64);
#pragma unroll
    for (int i = 0; i < 2; ++i) {
      int flat = i * 512 + t; int n = flat >> 3, c = flat & 7;
      xout[(size_t)n * 8 + c] = *(const uint4*)(L + 16384 + n * 128 + SWZ(n, c * 16));
    }
  }
  if (t < 64) {
    const float* R = (const float*)(L + 33792);
    float v = fmaxf(R[t], R[64 + t]);
    rmOut[(size_t)(blockIdx.x * 2 + 0) * 64 + t] = v;   // duplicated partials so all
    rmOut[(size_t)(blockIdx.x * 2 + 1) * 64 + t] = v;   // consumers fmax a pair
  }
}

// ---------- fused pass: 64 nodes / 256 threads ----------
// LDS: XL@0 (8K), P@8192 (8K), U@16384 (8K), RED@24576 (2K) = 26624 B
#define PXL 0
#define PP  8192
#define PU  16384
#define PRED 24576

__global__ __launch_bounds__(256, 5) void pass_kernel(
    ushort* __restrict__ xG, const ushort* __restrict__ gwF,
    const float* __restrict__ rmP, const float* __restrict__ cmG, int mode,
    int s_w1, int s_w2, int s_ih0, int s_hh0,
    const float* __restrict__ b1, const float* __restrict__ b2,
    const float* __restrict__ gg, const float* __restrict__ be,
    const float* __restrict__ bih, const float* __restrict__ bhh,
    float* __restrict__ rmOut) {
  __shared__ __align__(16) unsigned char L[26624];
  const int t = threadIdx.x;
  const int ws = t >> 6, l = t & 63, lq = l >> 4, lr = l & 15;
  const int gbase = blockIdx.x * 64;
  const int j0 = ws * 16 + lq * 4;
  const int colb = ws * 32 + lq * 8;
  const int rowp = (gbase >> 7) * 2;            // first partial slot of this row
  const int b = gbase >> 15;
  const int k1b = gbase & 127;

  const ushort* Aw1 = gwF + (size_t)s_w1 * 4096;
  const ushort* Aw2 = gwF + (size_t)s_w2 * 4096;
  const ushort* Ai0 = gwF + (size_t)s_ih0 * 4096;
  const ushort* Ai1 = Ai0 + 4096;
  const ushort* Ai2 = Ai1 + 4096;
  const ushort* Ah0 = gwF + (size_t)s_hh0 * 4096;
  const ushort* Ah1 = Ah0 + 4096;
  const ushort* Ah2 = Ah1 + 4096;

  { // stage x -> XL, (x - mv) -> P   (512 uint4 chunks / 256 threads)
    const uint4* xrow = (const uint4*)(xG + (size_t)gbase * 64);
#pragma unroll
    for (int i = 0; i < 2; ++i) {
      int flat = i * 256 + t; int n = flat >> 3, c = flat & 7;
      uint4 xv = xrow[(size_t)n * 8 + c];
      *(uint4*)(L + PXL + n * 128 + SWZ(n, c * 16)) = xv;
      float mv[8];
      if (mode == 0) {
        const float* r0 = rmP + (size_t)rowp * 64 + c * 8;
#pragma unroll
        for (int q = 0; q < 8; ++q) mv[q] = fmaxf(r0[q], r0[64 + q]);
      } else {
        const float* cp = cmG + ((size_t)(b * 128 + k1b + n)) * 64 + c * 8;
#pragma unroll
        for (int q = 0; q < 8; ++q) mv[q] = cp[q];
      }
      uint4 o;
      o.x = pk2(bflo(xv.x) - mv[0], bfhi(xv.x) - mv[1]);
      o.y = pk2(bflo(xv.y) - mv[2], bfhi(xv.y) - mv[3]);
      o.z = pk2(bflo(xv.z) - mv[4], bfhi(xv.z) - mv[5]);
      o.w = pk2(bflo(xv.w) - mv[6], bfhi(xv.w) - mv[7]);
      *(uint4*)(L + PP + n * 128 + SWZ(n, c * 16)) = o;
    }
  }
  __syncthreads();                                   // B0

  // GEMM1: h1 = W1 * (x - mv) + b1
  f32x4 acc[4];
  { float4 v = *(const float4*)(b1 + j0); binit(acc, v.x, v.y, v.z, v.w); }
  gemmG(Aw1, L, PP, ws, l, lq, lr, acc);
#pragma unroll
  for (int nt = 0; nt < 4; ++nt) {
    float s = acc[nt][0] + acc[nt][1] + acc[nt][2] + acc[nt][3];
    float q = acc[nt][0] * acc[nt][0] + acc[nt][1] * acc[nt][1] +
              acc[nt][2] * acc[nt][2] + acc[nt][3] * acc[nt][3];
    s += __shfl_xor(s, 16); q += __shfl_xor(q, 16);
    s += __shfl_xor(s, 32); q += __shfl_xor(q, 32);
    if (lq == 0)
      *(float2*)(L + PRED + (ws * 64 + nt * 16 + lr) * 8) = make_float2(s, q);
  }
  __syncthreads();                                   // B1
  { // LN + ReLU -> P (h)  (GEMM1's P reads all completed before B1)
    float4 vg = *(const float4*)(gg + j0);
    float4 vbe = *(const float4*)(be + j0);
    float gv[4] = {vg.x, vg.y, vg.z, vg.w};
    float bv[4] = {vbe.x, vbe.y, vbe.z, vbe.w};
#pragma unroll
    for (int nt = 0; nt < 4; ++nt) {
      int np = nt * 16 + lr;
      float ss = 0.f, qq = 0.f;
#pragma unroll
      for (int wv = 0; wv < 4; ++wv) {
        float2 pr = *(const float2*)(L + PRED + (wv * 64 + np) * 8);
        ss += pr.x; qq += pr.y;
      }
      float mean = ss * (1.f / 64.f);
      float rstd = rsqrtf(qq * (1.f / 64.f) - mean * mean + 1e-5f);
      float h_[4];
#pragma unroll
      for (int r = 0; r < 4; ++r) h_[r] = relu((acc[nt][r] - mean) * rstd * gv[r] + bv[r]);
      *(uint2*)(L + PP + np * 128 + SWZ(np, colb)) =
          make_uint2(pk2(h_[0], h_[1]), pk2(h_[2], h_[3]));
    }
  }
  __syncthreads();                                   // B2
  __builtin_amdgcn_sched_barrier(0);                 // fence: no A-load hoist above

  // GEMM2: u = W2 * h + b2 ; write u -> U (separate buffer: no WAR barrier needed)
  { float4 v = *(const float4*)(b2 + j0); binit(acc, v.x, v.y, v.z, v.w); }
  gemmG(Aw2, L, PP, ws, l, lq, lr, acc);
#pragma unroll
  for (int nt = 0; nt < 4; ++nt) {
    int n = nt * 16 + lr;
    *(uint2*)(L + PU + n * 128 + SWZ(n, colb)) =
        make_uint2(pk2(acc[nt][0], acc[nt][1]), pk2(acc[nt][2], acc[nt][3]));
  }
  __builtin_amdgcn_sched_barrier(0);                 // fence

  // ah = bh_n + Whh_n * x  (reads XL only -> overlaps with other waves' U writes)
  f32x4 ah[4];
  { float4 v = *(const float4*)(bhh + 128 + j0); binit(ah, v.x, v.y, v.z, v.w); }
  gemmG(Ah2, L, PXL, ws, l, lq, lr, ah);
  __syncthreads();                                   // B3: U published
  __builtin_amdgcn_sched_barrier(0);                 // fence

  f32x4 ar[4];                                       // r = sigm(Wih_r*u + Whh_r*x + b)
  { float4 vi = *(const float4*)(bih + j0);
    float4 vh = *(const float4*)(bhh + j0);
    binit(ar, vi.x + vh.x, vi.y + vh.y, vi.z + vh.z, vi.w + vh.w); }
  gemmG(Ai0, L, PU, ws, l, lq, lr, ar);
  gemmG(Ah0, L, PXL, ws, l, lq, lr, ar);
  __builtin_amdgcn_sched_barrier(0);                 // fence

  f32x4 an[4];                                       // an = bi_n + r*ah; += Wih_n*u
  { float4 v = *(const float4*)(bih + 128 + j0);
    float bv[4] = {v.x, v.y, v.z, v.w};
#pragma unroll
    for (int nt = 0; nt < 4; ++nt)
#pragma unroll
      for (int r = 0; r < 4; ++r)
        an[nt][r] = bv[r] + sigm(ar[nt][r]) * ah[nt][r];
  }
  gemmG(Ai2, L, PU, ws, l, lq, lr, an);
  __builtin_amdgcn_sched_barrier(0);                 // fence

  f32x4 az[4];                                       // z gate
  { float4 vi = *(const float4*)(bih + 64 + j0);
    float4 vh = *(const float4*)(bhh + 64 + j0);
    binit(az, vi.x + vh.x, vi.y + vh.y, vi.z + vh.z, vi.w + vh.w); }
  gemmG(Ai1, L, PU, ws, l, lq, lr, az);
  gemmG(Ah1, L, PXL, ws, l, lq, lr, az);

  // epilogue: xn from registers, direct global stores (no LDS roundtrip, no barriers)
  float xn[4][4];
#pragma unroll
  for (int nt = 0; nt < 4; ++nt) {
    int n = nt * 16 + lr;
    uint2 xo = *(const uint2*)(L + PXL + n * 128 + SWZ(n, colb));
    float xv[4] = {bflo(xo.x), bfhi(xo.x), bflo(xo.y), bfhi(xo.y)};
#pragma unroll
    for (int r = 0; r < 4; ++r) {
      float nn = tanh_f(an[nt][r]);
      float zz = sigm(az[nt][r]);
      xn[nt][r] = nn + zz * (xv[r] - nn);
    }
  }
  {
    ushort* xout = xG + (size_t)gbase * 64;
#pragma unroll
    for (int nt = 0; nt < 4; ++nt) {
      int n = nt * 16 + lr;
      *(uint2*)(xout + (size_t)n * 64 + j0) =
          make_uint2(pk2(xn[nt][0], xn[nt][1]), pk2(xn[nt][2], xn[nt][3]));
    }
  }
  { // row-max partial over this block's 64 nodes
    float mt[4];
#pragma unroll
    for (int r = 0; r < 4; ++r)
      mt[r] = fmaxf(fmaxf(xn[0][r], xn[1][r]), fmaxf(xn[2][r], xn[3][r]));
#pragma unroll
    for (int m = 1; m < 16; m <<= 1)
#pragma unroll
      for (int r = 0; r < 4; ++r) mt[r] = fmaxf(mt[r], __shfl_xor(mt[r], m));
    if (lr == 0) {
      float4 v; v.x = mt[0]; v.y = mt[1]; v.z = mt[2]; v.w = mt[3];
      *(float4*)(rmOut + (size_t)blockIdx.x * 64 + j0) = v;
    }
  }
}

// ---------- colmax: cm[b][k1][k] = max over 256 m ----------
__global__ __launch_bounds__(256) void colmax_kernel(const ushort* __restrict__ xG,
                                                     float* __restrict__ cm) {
  const int t = threadIdx.x;
  const int b = blockIdx.x >> 4, kg = blockIdx.x & 15;
  const int col = t & 31, k1 = kg * 8 + (t >> 5);
  const u32* xu = (const u32*)xG;
  float m0 = -INFINITY, m1 = -INFINITY;
  for (int m = 0; m < 256; ++m) {
    size_t node = ((size_t)(b * 256 + m)) * 128 + k1;
    u32 v = xu[node * 32 + col];
    m0 = fmaxf(m0, bflo(v)); m1 = fmaxf(m1, bfhi(v));
  }
  float* dst = cm + ((size_t)(b * 128 + k1)) * 64 + col * 2;
  dst[0] = m0; dst[1] = m1;
}

// ---------- top-level GRU (folds global max from 512 partials per b) ----------
__global__ __launch_bounds__(64) void topgru_kernel(
    const float* __restrict__ rm, const float* __restrict__ hs,
    const float* __restrict__ gwih, const float* __restrict__ gwhh,
    const float* __restrict__ gbih, const float* __restrict__ gbhh,
    float* __restrict__ nh, float* __restrict__ outTail) {
  __shared__ float gf[64], h0[64];
  const int b = blockIdx.x, j = threadIdx.x;
  float g0 = -INFINITY, g1 = -INFINITY, g2 = -INFINITY, g3 = -INFINITY;
  const float* base = rm + (size_t)b * 512 * 64 + j;
  for (int r = 0; r < 512; r += 4) {
    g0 = fmaxf(g0, base[(r + 0) * 64]);
    g1 = fmaxf(g1, base[(r + 1) * 64]);
    g2 = fmaxf(g2, base[(r + 2) * 64]);
    g3 = fmaxf(g3, base[(r + 3) * 64]);
  }
  gf[j] = fmaxf(fmaxf(g0, g1), fmaxf(g2, g3));
  h0[j] = hs[b * 64 + j];
  __syncthreads();
  float gi[3], gh[3];
#pragma unroll
  for (int g = 0; g < 3; ++g) {
    float s = gbih[g * 64 + j];
    const float* wr = gwih + (g * 64 + j) * 64;
    for (int k = 0; k < 64; ++k) s += wr[k] * gf[k];
    gi[g] = s;
  }
#pragma unroll
  for (int g = 0; g < 3; ++g) {
    float s = gbhh[g * 64 + j];
    const float* wr = gwhh + (g * 64 + j) * 64;
    for (int k = 0; k < 64; ++k) s += wr[k] * h0[k];
    gh[g] = s;
  }
  float rr = sigm(gi[0] + gh[0]);
  float zz = sigm(gi[1] + gh[1]);
  float nn = tanh_f(gi[2] + rr * gh[2]);
  float val = (1.0f - zz) * nn + zz * h0[j];
  nh[b * 64 + j] = val;
  outTail[b * 64 + j] = val;
}

// ---------- head constant: hc[b][j] = head_b1[j] + head_w1[j,64:] @ nh[b] ----------
__global__ __launch_bounds__(64) void hc_kernel(const float* __restrict__ nh,
                                                const float* __restrict__ hw1,
                                                const float* __restrict__ hb1,
                                                float* __restrict__ hc) {
  __shared__ float h0[64];
  const int b = blockIdx.x, j = threadIdx.x;
  h0[j] = nh[b * 64 + j];
  __syncthreads();
  float s = hb1[j];
  const float* wr = hw1 + j * 128 + 64;
  for (int k = 0; k < 64; ++k) s += wr[k] * h0[k];
  hc[b * 64 + j] = s;
}

// ---------- head: logits (128 nodes / 512 threads) ----------
__global__ __launch_bounds__(512) void head_kernel(
    const ushort* __restrict__ xG, const ushort* __restrict__ gwF,
    const float* __restrict__ hc, const float* __restrict__ hw2,
    const float* __restrict__ hb2, float* __restrict__ out) {
  __shared__ __align__(16) unsigned char L[18432];
  const int t = threadIdx.x;
  const int w = t >> 6, l = t & 63, lq = l >> 4, lr = l & 15;
  const int ws = w & 3, nh = w >> 2;
  const int gbase = blockIdx.x * 128;
  const int b = gbase >> 15;
  const int j0 = ws * 16 + lq * 4;

  { const uint4* xrow = (const uint4*)(xG + (size_t)gbase * 64);
#pragma unroll
    for (int i = 0; i < 2; ++i) {
      int flat = i * 512 + t; int n = flat >> 3, c = flat & 7;
      *(uint4*)(L + n * 128 + SWZ(n, c * 16)) = xrow[(size_t)n * 8 + c];
    } }
  __syncthreads();

  float4 vhc = *(const float4*)(hc + b * 64 + j0);
  f32x4 acc[4];
  binit(acc, vhc.x, vhc.y, vhc.z, vhc.w);
  gemmG2(gwF + 4096, L, 0, ws, nh, l, lq, lr, acc);   // slice 1 = head_w1[:, :64]

  float4 w2v = *(const float4*)(hw2 + j0);
  float w2a[4] = {w2v.x, w2v.y, w2v.z, w2v.w};
#pragma unroll
  for (int nt = 0; nt < 4; ++nt) {
    float p = 0.f;
#pragma unroll
    for (int r = 0; r < 4; ++r) p += w2a[r] * relu(acc[nt][r]);
    p += __shfl_xor(p, 16);
    p += __shfl_xor(p, 32);
    if (lq == 0) ((float*)(L + 16384))[(nh * 4 + ws) * 64 + nt * 16 + lr] = p;
  }
  __syncthreads();
  if (t < 128) {
    const float* red = (const float*)(L + 16384) + (t >> 6) * 256 + (t & 63);
    out[gbase + t] = red[0] + red[64] + red[128] + red[192] + hb2[0];
  }
}

// ---------- host ----------
extern "C" void kernel_launch(void* const* d_in, const int* in_sizes, int n_in,
                              void* d_out, int out_size, void* d_ws, size_t ws_size,
                              hipStream_t stream) {
  const float* hybrid   = (const float*)d_in[0];
  const float* hidden   = (const float*)d_in[1];
  const float* enc_w1   = (const float*)d_in[2];
  const float* enc_b1   = (const float*)d_in[3];
  const float* enc_g    = (const float*)d_in[4];
  const float* enc_beta = (const float*)d_in[5];
  const float* enc_w2   = (const float*)d_in[6];
  const float* enc_b2   = (const float*)d_in[7];
  const float* l_w1     = (const float*)d_in[8];
  const float* l_b1     = (const float*)d_in[9];
  const float* l_g      = (const float*)d_in[10];
  const float* l_beta   = (const float*)d_in[11];
  const float* l_w2     = (const float*)d_in[12];
  const float* l_b2     = (const float*)d_in[13];
  const float* l_gwih   = (const float*)d_in[14];
  const float* l_gwhh   = (const float*)d_in[15];
  const float* l_gbih   = (const float*)d_in[16];
  const float* l_gbhh   = (const float*)d_in[17];
  const float* g_wih    = (const float*)d_in[18];
  const float* g_whh    = (const float*)d_in[19];
  const float* g_bih    = (const float*)d_in[20];
  const float* g_bhh    = (const float*)d_in[21];
  const float* head_w1  = (const float*)d_in[22];
  const float* head_b1  = (const float*)d_in[23];
  const float* head_w2  = (const float*)d_in[24];
  const float* head_b2  = (const float*)d_in[25];

  char* p = (char*)d_ws;
  size_t off = 0;
  auto carve = [&](size_t bytes) { void* r = p + off; off = (off + bytes + 255) & ~255ULL; return r; };
  ushort* xG  = (ushort*)carve((size_t)NTOT * 64 * 2);     // 128 MiB node-major bf16
  ushort* gwF = (ushort*)carve(34 * 4096 * 2);
  float*  rmA = (float*)carve((size_t)16384 * 64 * 4);     // row-max partials (dbuf A)
  float*  rmB = (float*)carve((size_t)16384 * 64 * 4);     // row-max partials (dbuf B)
  float*  cmG = (float*)carve((size_t)32 * 128 * 64 * 4);
  float*  nh  = (float*)carve(2048 * 4);
  float*  hcb = (float*)carve(2048 * 4);

  if (ws_size < off) {
    diag_kernel<<<1, 1, 0, stream>>>((float*)d_out, 1.0f + (float)ws_size * 1e-9f);
    return;
  }

  prep_kernel<<<34, 256, 0, stream>>>(enc_w2, head_w1, l_w1, l_w2, l_gwih, l_gwhh, gwF);
  encoder_kernel<<<8192, 512, 0, stream>>>((const float4*)hybrid, xG, gwF, enc_w1,
                                           enc_b1, enc_g, enc_beta, enc_b2, rmA);

  // rm double-buffer: pass reads rmRead, writes rmWrite (avoids intra-kernel races)
  float* rmRead = rmA;
  float* rmWrite = rmB;
  for (int lyr = 0; lyr < 2; ++lyr) {
    for (int s = 0; s < 2; ++s) {
      const int m = lyr * 2 + s;
      if (s == 1) colmax_kernel<<<512, 256, 0, stream>>>(xG, cmG);
      pass_kernel<<<16384, 256, 0, stream>>>(
          xG, gwF, rmRead, cmG, s,
          2 + m, 6 + m, 10 + 3 * m, 22 + 3 * m,
          l_b1 + m * 64, l_b2 + m * 64, l_g + m * 64, l_beta + m * 64,
          l_gbih + m * 192, l_gbhh + m * 192, rmWrite);
      float* tmp = rmRead; rmRead = rmWrite; rmWrite = tmp;
    }
  }

  topgru_kernel<<<32, 64, 0, stream>>>(rmRead, hidden, g_wih, g_whh, g_bih, g_bhh,
                                       nh, (float*)d_out + 1048576);
  hc_kernel<<<32, 64, 0, stream>>>(nh, head_w1, head_b1, hcb);
  head_kernel<<<8192, 512, 0, stream>>>(xG, gwF, hcb, head_w2, head_b2, (float*)d_out);
}